// Round 1
// baseline (208.183 us; speedup 1.0000x reference)
//
#include <hip/hip_runtime.h>
#include <hip/hip_bf16.h>
#include <stdint.h>
#include <stddef.h>

#define T_S 4096
#define D_M 1024
#define NH_ 16
#define EPSF 1.1920929e-07f

typedef float f32x4 __attribute__((ext_vector_type(4)));
typedef __bf16 bf16x8 __attribute__((ext_vector_type(8)));
typedef short short8 __attribute__((ext_vector_type(8)));
typedef unsigned short ushort4v __attribute__((ext_vector_type(4)));

static __device__ __forceinline__ unsigned short f2bf(float f) {
  unsigned int u = __builtin_bit_cast(unsigned int, f);
  unsigned int r = (u + 0x7fffu + ((u >> 16) & 1u)) >> 16;
  return (unsigned short)r;
}
static __device__ __forceinline__ float bf2f(unsigned short s) {
  unsigned int u = ((unsigned int)s) << 16;
  return __builtin_bit_cast(float, u);
}

#define GLDS16(gp, lp) __builtin_amdgcn_global_load_lds( \
    (__attribute__((address_space(1))) void*)(gp),       \
    (__attribute__((address_space(3))) void*)(lp), 16, 0, 0)

static __device__ __forceinline__ f32x4 mfma16(bf16x8 a, bf16x8 b, f32x4 c) {
  return __builtin_amdgcn_mfma_f32_16x16x32_bf16(a, b, c, 0, 0, 0);
}

// ---------------- RoPE cos/sin table: [T][32] ----------------
__global__ __launch_bounds__(256) void k_rope_tab(float* __restrict__ cosT,
                                                  float* __restrict__ sinT) {
  int i = blockIdx.x * 256 + threadIdx.x;  // t*32 + f
  int t = i >> 5, f = i & 31;
  float fr = (f < 16) ? powf(1e-4f, (float)f * (1.0f / 15.0f)) : 0.0f;
  float th = (float)t * fr;
  cosT[i] = cosf(th);
  sinT[i] = sinf(th);
}

// ---------------- f32 -> bf16 (exact grid, no tail) ----------------
__global__ __launch_bounds__(256) void k_f32_to_bf16(const float* __restrict__ src,
                                                     unsigned short* __restrict__ dst) {
  int i = blockIdx.x * 256 + threadIdx.x;
  float4 v = ((const float4*)src)[i];
  ushort4v o;
  o.x = f2bf(v.x); o.y = f2bf(v.y); o.z = f2bf(v.z); o.w = f2bf(v.w);
  ((ushort4v*)dst)[i] = o;
}

// ---------------- RMSNorm over D=1024 + cast, one block per token ----------------
__global__ __launch_bounds__(256) void k_rmsnorm_cast(const float* __restrict__ x,
                                                      unsigned short* __restrict__ xn) {
  const int row = blockIdx.x;
  const int tid = threadIdx.x;
  float4 v = ((const float4*)(x + (size_t)row * D_M))[tid];
  float ss = v.x * v.x + v.y * v.y + v.z * v.z + v.w * v.w;
#pragma unroll
  for (int d = 1; d < 64; d <<= 1) ss += __shfl_xor(ss, d, 64);
  __shared__ float red[4];
  if ((tid & 63) == 0) red[tid >> 6] = ss;
  __syncthreads();
  float sc = rsqrtf((red[0] + red[1] + red[2] + red[3]) * (1.0f / D_M) + EPSF);
  ushort4v o;
  o.x = f2bf(v.x * sc); o.y = f2bf(v.y * sc); o.z = f2bf(v.z * sc); o.w = f2bf(v.w * sc);
  ((ushort4v*)(xn + (size_t)row * D_M))[tid] = o;
}

// ---------------- bf16 GEMM, C = A @ B^T   (A:[M,K], B:[N,K] row-major) ----------------
// EPI 0: scatter qkv -> q/k/v head-major bf16 buffers [n,h,t,d]
// EPI 1: Cf = resid + scale[col]*acc  (f32)
template <int EPI>
__global__ __launch_bounds__(256) void k_gemm_bt(
    const unsigned short* __restrict__ A, const unsigned short* __restrict__ B,
    unsigned short* __restrict__ q_out, unsigned short* __restrict__ k_out,
    unsigned short* __restrict__ v_out, float* __restrict__ Cf,
    const float* __restrict__ resid, const float* __restrict__ scale,
    int M, int Ncols, int K) {
  __shared__ __align__(16) unsigned short As[128 * 32];
  __shared__ __align__(16) unsigned short Bs[128 * 32];
  const int tid = threadIdx.x;
  const int lane = tid & 63, w = tid >> 6;
  const int lrow = lane & 15, lk8 = (lane >> 4) * 8;
  const int m0 = blockIdx.y * 128, n0 = blockIdx.x * 128;
  const int wr = (w >> 1) * 64, wc = (w & 1) * 64;
  f32x4 acc[4][4] = {};

  const int ldsoff0 = w * 2048;                 // wave-uniform staging base (bytes)
  const int eoff0 = (ldsoff0 >> 1) + lane * 8;  // per-lane element offset in tile

  for (int kt = 0; kt < K; kt += 32) {
    const unsigned short* Ab = A + (size_t)m0 * K + kt;
    const unsigned short* Bb = B + (size_t)n0 * K + kt;
#pragma unroll
    for (int i = 0; i < 2; ++i) {
      int ldsoff = ldsoff0 + i * 1024;
      int eoff = eoff0 + i * 512;
      int r = eoff >> 5, cc = eoff & 31;
      GLDS16(Ab + (size_t)r * K + cc, (char*)As + ldsoff);
      GLDS16(Bb + (size_t)r * K + cc, (char*)Bs + ldsoff);
    }
    __syncthreads();
    bf16x8 aF[4], bF[4];
#pragma unroll
    for (int mi = 0; mi < 4; ++mi)
      aF[mi] = *(const bf16x8*)&As[(wr + mi * 16 + lrow) * 32 + lk8];
#pragma unroll
    for (int ni = 0; ni < 4; ++ni)
      bF[ni] = *(const bf16x8*)&Bs[(wc + ni * 16 + lrow) * 32 + lk8];
#pragma unroll
    for (int mi = 0; mi < 4; ++mi)
#pragma unroll
      for (int ni = 0; ni < 4; ++ni)
        acc[mi][ni] = mfma16(aF[mi], bF[ni], acc[mi][ni]);
    __syncthreads();
  }

  const int r0 = m0 + wr + ((lane >> 4) << 2);  // + mi*16 + j   (= n*T + t)
  const int c0 = n0 + wc + lrow;                // + ni*16

  if (EPI == 0) {
#pragma unroll
    for (int mi = 0; mi < 4; ++mi)
#pragma unroll
      for (int ni = 0; ni < 4; ++ni) {
        int col = c0 + ni * 16;
        int which = col >> 10;
        int hh = (col >> 6) & 15;
        int dd = col & 63;
        unsigned short* dst = (which == 0) ? q_out : ((which == 1) ? k_out : v_out);
#pragma unroll
        for (int j = 0; j < 4; ++j) {
          int row = r0 + mi * 16 + j;
          size_t off =
              ((size_t)((row >> 12) * NH_ + hh) * T_S + (row & (T_S - 1))) * 64 + dd;
          dst[off] = f2bf(acc[mi][ni][j]);
        }
      }
  } else {
#pragma unroll
    for (int mi = 0; mi < 4; ++mi)
#pragma unroll
      for (int ni = 0; ni < 4; ++ni) {
        int col = c0 + ni * 16;
        float sc = scale[col];
#pragma unroll
        for (int j = 0; j < 4; ++j) {
          int row = r0 + mi * 16 + j;
          size_t idx = (size_t)row * Ncols + col;
          Cf[idx] = resid[idx] + sc * acc[mi][ni][j];
        }
      }
  }
}

// ---------------- per-head RMSNorm + RoPE, in place on q/k head-major buffers ----------------
__global__ __launch_bounds__(256) void k_rope_qk(unsigned short* __restrict__ qh,
                                                 unsigned short* __restrict__ kh,
                                                 const float* __restrict__ cosT,
                                                 const float* __restrict__ sinT) {
  int wid = (blockIdx.x * 256 + threadIdx.x) >> 6;  // nh*T + t,  nh = n*16+h
  int lane = threadIdx.x & 63;
  int t = wid & (T_S - 1);
  size_t base = (size_t)wid * 64 + lane;
  float qv = bf2f(qh[base]);
  float kv = bf2f(kh[base]);
  float qs = qv * qv, ks = kv * kv;
#pragma unroll
  for (int d = 1; d < 64; d <<= 1) {
    qs += __shfl_xor(qs, d, 64);
    ks += __shfl_xor(ks, d, 64);
  }
  qv *= rsqrtf(qs * (1.0f / 64.0f) + EPSF);
  kv *= rsqrtf(ks * (1.0f / 64.0f) + EPSF);
  int f = lane & 31;
  float cs = cosT[t * 32 + f], sn = sinT[t * 32 + f];
  float qp = __shfl_xor(qv, 32, 64);
  float kp = __shfl_xor(kv, 32, 64);
  float qo, ko;
  if (lane < 32) {
    qo = qv * cs + qp * sn;
    ko = kv * cs + kp * sn;
  } else {
    qo = qv * cs - qp * sn;
    ko = kv * cs - kp * sn;
  }
  qh[base] = f2bf(qo);
  kh[base] = f2bf(ko);
}

// ---------------- chunked sliding-window attention ----------------
// block = (n,h,c): 4 waves x 32 q-rows; keys = 256 (prev chunk + cur chunk)
__global__ __launch_bounds__(256) void k_attn(const unsigned short* __restrict__ qh,
                                              const unsigned short* __restrict__ kh,
                                              const unsigned short* __restrict__ vh,
                                              unsigned short* __restrict__ ao) {
  extern __shared__ __align__(16) char lds[];
  unsigned short* Vt = (unsigned short*)lds;                    // [64][264]
  unsigned short* Pb = (unsigned short*)(lds + 64 * 264 * 2);   // 4 x [32][72]
  const int b = blockIdx.x;
  const int c = b & 31, nh = b >> 5;  // nh = n*16+h
  const int tid = threadIdx.x, lane = tid & 63, w = tid >> 6;
  const int lrow = lane & 15, g = lane >> 4, lk8 = g * 8;
  const size_t hb = (size_t)nh * T_S * 64;
  const unsigned short* qg = qh + hb + (size_t)c * 128 * 64;
  const unsigned short* kg = kh + hb + ((ptrdiff_t)c * 128 - 128) * 64;
  const unsigned short* vg = vh + hb + ((ptrdiff_t)c * 128 - 128) * 64;

  // stage V transposed: Vt[d][m], stride 264 (16B-aligned rows, bank-uniform)
#pragma unroll
  for (int it = 0; it < 8; ++it) {
    int chunk = tid + it * 256;  // 0..2047
    int m = chunk >> 3, d0 = (chunk & 7) * 8;
    short8 v = {0, 0, 0, 0, 0, 0, 0, 0};
    if (!(c == 0 && m < 128)) v = *(const short8*)(vg + (size_t)m * 64 + d0);
#pragma unroll
    for (int j = 0; j < 8; ++j) Vt[(d0 + j) * 264 + m] = (unsigned short)v[j];
  }

  // Q fragments (rows w*32..w*32+31), straight from global
  bf16x8 qf[2][2];
#pragma unroll
  for (int mi = 0; mi < 2; ++mi)
#pragma unroll
    for (int ks = 0; ks < 2; ++ks)
      qf[mi][ks] =
          *(const bf16x8*)(qg + (size_t)(w * 32 + mi * 16 + lrow) * 64 + ks * 32 + lk8);

  // S = Q K^T  (C/D layout: col=key=lane&15, row=q=(lane>>4)*4+reg)
  f32x4 s[2][16] = {};
#pragma unroll
  for (int ni = 0; ni < 16; ++ni) {
    if (c == 0 && ni < 8) continue;  // masked & would be OOB
    bf16x8 kf0 = *(const bf16x8*)(kg + (size_t)(ni * 16 + lrow) * 64 + lk8);
    bf16x8 kf1 = *(const bf16x8*)(kg + (size_t)(ni * 16 + lrow) * 64 + 32 + lk8);
#pragma unroll
    for (int mi = 0; mi < 2; ++mi) {
      s[mi][ni] = mfma16(qf[mi][0], kf0, s[mi][ni]);
      s[mi][ni] = mfma16(qf[mi][1], kf1, s[mi][ni]);
    }
  }

  // mask + scale + row softmax (row = 16 lanes x 16 ni-regs)
#pragma unroll
  for (int mi = 0; mi < 2; ++mi) {
#pragma unroll
    for (int j = 0; j < 4; ++j) {
      int jq = w * 32 + mi * 16 + g * 4 + j;
      float mx = -1e30f;
#pragma unroll
      for (int ni = 0; ni < 16; ++ni) {
        int m = ni * 16 + lrow;
        bool ok = (m > jq) && (m <= 128 + jq) && (c > 0 || m >= 128);
        float val = ok ? s[mi][ni][j] * 0.125f : -1e30f;
        s[mi][ni][j] = val;
        mx = fmaxf(mx, val);
      }
#pragma unroll
      for (int d2 = 1; d2 < 16; d2 <<= 1) mx = fmaxf(mx, __shfl_xor(mx, d2, 64));
      float sum = 0.0f;
#pragma unroll
      for (int ni = 0; ni < 16; ++ni) {
        float p = __expf(s[mi][ni][j] - mx);
        s[mi][ni][j] = p;
        sum += p;
      }
#pragma unroll
      for (int d2 = 1; d2 < 16; d2 <<= 1) sum += __shfl_xor(sum, d2, 64);
      float inv = 1.0f / sum;
#pragma unroll
      for (int ni = 0; ni < 16; ++ni) s[mi][ni][j] *= inv;
    }
  }

  __syncthreads();  // Vt fully staged before PV reads

  // PV in 64-key quarters; P staged per-wave in LDS (stride 72)
  f32x4 oacc[2][4] = {};
  unsigned short* Pw = Pb + w * (32 * 72);
#pragma unroll
  for (int qi = 0; qi < 4; ++qi) {
#pragma unroll
    for (int mi = 0; mi < 2; ++mi)
#pragma unroll
      for (int ni4 = 0; ni4 < 4; ++ni4) {
        int ni = qi * 4 + ni4;
#pragma unroll
        for (int j = 0; j < 4; ++j) {
          int r = mi * 16 + g * 4 + j;
          Pw[r * 72 + ni4 * 16 + lrow] = f2bf(s[mi][ni][j]);
        }
      }
    // per-wave private region: lgkmcnt ordering suffices (no cross-wave barrier)
#pragma unroll
    for (int ks = 0; ks < 2; ++ks) {
      bf16x8 pf[2], vf[4];
#pragma unroll
      for (int mi = 0; mi < 2; ++mi)
        pf[mi] = *(const bf16x8*)&Pw[(mi * 16 + lrow) * 72 + ks * 32 + lk8];
#pragma unroll
      for (int nj = 0; nj < 4; ++nj)
        vf[nj] = *(const bf16x8*)&Vt[(nj * 16 + lrow) * 264 + qi * 64 + ks * 32 + lk8];
#pragma unroll
      for (int mi = 0; mi < 2; ++mi)
#pragma unroll
        for (int nj = 0; nj < 4; ++nj)
          oacc[mi][nj] = mfma16(pf[mi], vf[nj], oacc[mi][nj]);
    }
  }

  // write attention out, token-major [n*T+t][h*64+d] bf16
  const int t0 = c * 128 + w * 32;
  const int n_ = nh >> 4, h_ = nh & 15;
#pragma unroll
  for (int mi = 0; mi < 2; ++mi)
#pragma unroll
    for (int nj = 0; nj < 4; ++nj)
#pragma unroll
      for (int j = 0; j < 4; ++j) {
        int t = t0 + mi * 16 + g * 4 + j;
        int dcol = nj * 16 + lrow;
        ao[((size_t)n_ * T_S + t) * D_M + h_ * 64 + dcol] = f2bf(oacc[mi][nj][j]);
      }
}

extern "C" void kernel_launch(void* const* d_in, const int* in_sizes, int n_in,
                              void* d_out, int out_size, void* d_ws, size_t ws_size,
                              hipStream_t stream) {
  const float* x = (const float*)d_in[0];      // [2,4096,1024]
  const float* qkvw = (const float*)d_in[1];   // [3,1024,1024]
  const float* ow = (const float*)d_in[2];     // [1024,1024]
  const float* osc = (const float*)d_in[3];    // [1024]
  float* out = (float*)d_out;

  char* ws = (char*)d_ws;
  unsigned short* xn = (unsigned short*)(ws + 0);            // 16,777,216
  unsigned short* qkvwb = (unsigned short*)(ws + 16777216);  //  6,291,456
  unsigned short* owb = (unsigned short*)(ws + 23068672);    //  2,097,152
  unsigned short* qhb = (unsigned short*)(ws + 25165824);    // 16,777,216
  unsigned short* khb = (unsigned short*)(ws + 41943040);    // 16,777,216
  unsigned short* vhb = (unsigned short*)(ws + 58720256);    // 16,777,216
  unsigned short* aob = (unsigned short*)(ws + 75497472);    // 16,777,216
  float* cosT = (float*)(ws + 92274688);                     //    524,288
  float* sinT = (float*)(ws + 92798976);                     //    524,288

  k_rope_tab<<<512, 256, 0, stream>>>(cosT, sinT);
  k_f32_to_bf16<<<3072, 256, 0, stream>>>(qkvw, qkvwb);
  k_f32_to_bf16<<<1024, 256, 0, stream>>>(ow, owb);
  k_rmsnorm_cast<<<8192, 256, 0, stream>>>(x, xn);
  k_gemm_bt<0><<<dim3(24, 64), 256, 0, stream>>>(xn, qkvwb, qhb, khb, vhb, nullptr,
                                                 nullptr, nullptr, 8192, 3072, 1024);
  k_rope_qk<<<32768, 256, 0, stream>>>(qhb, khb, cosT, sinT);
  k_attn<<<1024, 256, 52224, stream>>>(qhb, khb, vhb, aob);
  k_gemm_bt<1><<<dim3(8, 64), 256, 0, stream>>>(aob, owb, nullptr, nullptr, nullptr, out,
                                                x, osc, 8192, 1024, 1024);
}

// Round 2
// 188.636 us; speedup vs baseline: 1.1036x; 1.1036x over previous
//
#include <hip/hip_runtime.h>
#include <hip/hip_bf16.h>
#include <stdint.h>
#include <stddef.h>

#define T_S 4096
#define D_M 1024
#define NH_ 16
#define EPSF 1.1920929e-07f

typedef float f32x4 __attribute__((ext_vector_type(4)));
typedef __bf16 bf16x8 __attribute__((ext_vector_type(8)));
typedef short short8 __attribute__((ext_vector_type(8)));
typedef unsigned short ushort4v __attribute__((ext_vector_type(4)));

static __device__ __forceinline__ unsigned short f2bf(float f) {
  unsigned int u = __builtin_bit_cast(unsigned int, f);
  unsigned int r = (u + 0x7fffu + ((u >> 16) & 1u)) >> 16;
  return (unsigned short)r;
}
static __device__ __forceinline__ float bf2f(unsigned short s) {
  unsigned int u = ((unsigned int)s) << 16;
  return __builtin_bit_cast(float, u);
}

#define GLDS16(gp, lp) __builtin_amdgcn_global_load_lds( \
    (__attribute__((address_space(1))) void*)(gp),       \
    (__attribute__((address_space(3))) void*)(lp), 16, 0, 0)

static __device__ __forceinline__ f32x4 mfma16(bf16x8 a, bf16x8 b, f32x4 c) {
  return __builtin_amdgcn_mfma_f32_16x16x32_bf16(a, b, c, 0, 0, 0);
}

// ---------------- RoPE cos/sin table: [T][32] ----------------
__global__ __launch_bounds__(256) void k_rope_tab(float* __restrict__ cosT,
                                                  float* __restrict__ sinT) {
  int i = blockIdx.x * 256 + threadIdx.x;  // t*32 + f
  int t = i >> 5, f = i & 31;
  float fr = (f < 16) ? powf(1e-4f, (float)f * (1.0f / 15.0f)) : 0.0f;
  float th = (float)t * fr;
  cosT[i] = cosf(th);
  sinT[i] = sinf(th);
}

// ---------------- f32 -> bf16 (exact grid, no tail) ----------------
__global__ __launch_bounds__(256) void k_f32_to_bf16(const float* __restrict__ src,
                                                     unsigned short* __restrict__ dst) {
  int i = blockIdx.x * 256 + threadIdx.x;
  float4 v = ((const float4*)src)[i];
  ushort4v o;
  o.x = f2bf(v.x); o.y = f2bf(v.y); o.z = f2bf(v.z); o.w = f2bf(v.w);
  ((ushort4v*)dst)[i] = o;
}

// ---------------- RMSNorm over D=1024 + cast, one block per token ----------------
__global__ __launch_bounds__(256) void k_rmsnorm_cast(const float* __restrict__ x,
                                                      unsigned short* __restrict__ xn) {
  const int row = blockIdx.x;
  const int tid = threadIdx.x;
  float4 v = ((const float4*)(x + (size_t)row * D_M))[tid];
  float ss = v.x * v.x + v.y * v.y + v.z * v.z + v.w * v.w;
#pragma unroll
  for (int d = 1; d < 64; d <<= 1) ss += __shfl_xor(ss, d, 64);
  __shared__ float red[4];
  if ((tid & 63) == 0) red[tid >> 6] = ss;
  __syncthreads();
  float sc = rsqrtf((red[0] + red[1] + red[2] + red[3]) * (1.0f / D_M) + EPSF);
  ushort4v o;
  o.x = f2bf(v.x * sc); o.y = f2bf(v.y * sc); o.z = f2bf(v.z * sc); o.w = f2bf(v.w * sc);
  ((ushort4v*)(xn + (size_t)row * D_M))[tid] = o;
}

// ---------------- bf16 GEMM, C = A @ B^T, 3-stage pipeline, counted vmcnt ----------------
// BM=256, BN=128, BK=32; 8 waves (4M x 2N), wave tile 64x64; 3 LDS buffers.
// Ledger:
//  - stage of tile t+2 (into buf (t+2)%3) is issued during tile t, AFTER the
//    end-of-(t-1) barrier => cannot overwrite buf while tile t-1 readers active.
//  - reads of tile t+1 are covered by vmcnt(3) at end of tile t (only t+2's 3
//    loads may remain in flight), followed by s_barrier (per-wave vmcnt => all
//    waves' slices landed).
//  - LDS swizzle: linear slot S holds colgrp (S&3)^((S>>3)&3) of row S>>2
//    (inverse-permuted global source); ds_read uses byte = row*64 + ((g^((row>>1)&3))<<4).
// EPI 0: scatter qkv -> q/k/v head-major bf16 [n,h,t,d];  EPI 1: Cf = resid + scale[col]*acc.
template <int EPI>
__global__ __launch_bounds__(512) void k_gemm256(
    const unsigned short* __restrict__ A, const unsigned short* __restrict__ B,
    unsigned short* __restrict__ q_out, unsigned short* __restrict__ k_out,
    unsigned short* __restrict__ v_out, float* __restrict__ Cf,
    const float* __restrict__ resid, const float* __restrict__ scale,
    int M, int Ncols, int K) {
  extern __shared__ __align__(16) char lds[];  // 3 x (16384 A + 8192 B) = 73728 B
  const int tid = threadIdx.x;
  const int lane = tid & 63, w = tid >> 6;
  const int lrow = lane & 15, g = lane >> 4;
  const int wm = w >> 1, wn = w & 1;
  const int m0 = blockIdx.y * 256, n0 = blockIdx.x * 128;
  const int NT = K >> 5;

  // stage source offsets (elements), inverse-swizzled column group
  const int srcgrp = (((tid & 3) ^ ((tid >> 3) & 3)) << 3);
  const size_t aoff0 = (size_t)(m0 + (tid >> 2)) * K + srcgrp;
  const size_t aoff1 = aoff0 + (size_t)128 * K;
  const size_t boff = (size_t)(n0 + (tid >> 2)) * K + srcgrp;
  const int wbase = w * 1024;

  // ds_read byte offsets (per-thread constants)
  int abyte[4], bbyte[4];
#pragma unroll
  for (int i = 0; i < 4; ++i) {
    int ar = wm * 64 + i * 16 + lrow;
    abyte[i] = ar * 64 + ((g ^ ((ar >> 1) & 3)) << 4);
    int br = wn * 64 + i * 16 + lrow;
    bbyte[i] = 16384 + br * 64 + ((g ^ ((br >> 1) & 3)) << 4);
  }

  f32x4 acc[4][4] = {};

  // prologue: stage tile 0 -> buf0, tile 1 -> buf1
#pragma unroll
  for (int t = 0; t < 2; ++t) {
    char* sp = lds + t * 24576;
    GLDS16(A + aoff0 + t * 32, sp + wbase);
    GLDS16(A + aoff1 + t * 32, sp + 8192 + wbase);
    GLDS16(B + boff + t * 32, sp + 16384 + wbase);
  }
  asm volatile("s_waitcnt vmcnt(3)" ::: "memory");
  __builtin_amdgcn_s_barrier();
  asm volatile("" ::: "memory");

  int cb = 0, sb = 49152;
  for (int t = 0; t < NT; ++t) {
    if (t + 2 < NT) {  // stage tile t+2
      const int kt2 = (t + 2) << 5;
      char* sp = lds + sb;
      GLDS16(A + aoff0 + kt2, sp + wbase);
      GLDS16(A + aoff1 + kt2, sp + 8192 + wbase);
      GLDS16(B + boff + kt2, sp + 16384 + wbase);
    }
    const char* cp = lds + cb;
    bf16x8 aF[4], bF[4];
#pragma unroll
    for (int i = 0; i < 4; ++i) aF[i] = *(const bf16x8*)(cp + abyte[i]);
#pragma unroll
    for (int i = 0; i < 4; ++i) bF[i] = *(const bf16x8*)(cp + bbyte[i]);
    __builtin_amdgcn_s_setprio(1);
#pragma unroll
    for (int mi = 0; mi < 4; ++mi)
#pragma unroll
      for (int ni = 0; ni < 4; ++ni)
        acc[mi][ni] = mfma16(aF[mi], bF[ni], acc[mi][ni]);
    __builtin_amdgcn_s_setprio(0);
    if (t + 2 < NT)
      asm volatile("s_waitcnt vmcnt(3)" ::: "memory");
    else
      asm volatile("s_waitcnt vmcnt(0)" ::: "memory");
    __builtin_amdgcn_s_barrier();
    asm volatile("" ::: "memory");
    cb += 24576; if (cb == 73728) cb = 0;
    sb += 24576; if (sb == 73728) sb = 0;
  }

  const int r0 = m0 + wm * 64 + g * 4;      // + mi*16 + j
  const int c0 = n0 + wn * 64 + lrow;       // + ni*16

  if (EPI == 0) {
#pragma unroll
    for (int mi = 0; mi < 4; ++mi)
#pragma unroll
      for (int ni = 0; ni < 4; ++ni) {
        int col = c0 + ni * 16;
        int which = col >> 10;
        int hh = (col >> 6) & 15;
        int dd = col & 63;
        unsigned short* dst = (which == 0) ? q_out : ((which == 1) ? k_out : v_out);
#pragma unroll
        for (int j = 0; j < 4; ++j) {
          int row = r0 + mi * 16 + j;
          size_t off =
              ((size_t)((row >> 12) * NH_ + hh) * T_S + (row & (T_S - 1))) * 64 + dd;
          dst[off] = f2bf(acc[mi][ni][j]);
        }
      }
  } else {
#pragma unroll
    for (int mi = 0; mi < 4; ++mi)
#pragma unroll
      for (int ni = 0; ni < 4; ++ni) {
        int col = c0 + ni * 16;
        float sc = scale[col];
#pragma unroll
        for (int j = 0; j < 4; ++j) {
          int row = r0 + mi * 16 + j;
          size_t idx = (size_t)row * Ncols + col;
          Cf[idx] = resid[idx] + sc * acc[mi][ni][j];
        }
      }
  }
}

// ---------------- per-head RMSNorm + RoPE, in place on q/k head-major buffers ----------------
__global__ __launch_bounds__(256) void k_rope_qk(unsigned short* __restrict__ qh,
                                                 unsigned short* __restrict__ kh,
                                                 const float* __restrict__ cosT,
                                                 const float* __restrict__ sinT) {
  int wid = (blockIdx.x * 256 + threadIdx.x) >> 6;  // nh*T + t,  nh = n*16+h
  int lane = threadIdx.x & 63;
  int t = wid & (T_S - 1);
  size_t base = (size_t)wid * 64 + lane;
  float qv = bf2f(qh[base]);
  float kv = bf2f(kh[base]);
  float qs = qv * qv, ks = kv * kv;
#pragma unroll
  for (int d = 1; d < 64; d <<= 1) {
    qs += __shfl_xor(qs, d, 64);
    ks += __shfl_xor(ks, d, 64);
  }
  qv *= rsqrtf(qs * (1.0f / 64.0f) + EPSF);
  kv *= rsqrtf(ks * (1.0f / 64.0f) + EPSF);
  int f = lane & 31;
  float cs = cosT[t * 32 + f], sn = sinT[t * 32 + f];
  float qp = __shfl_xor(qv, 32, 64);
  float kp = __shfl_xor(kv, 32, 64);
  float qo, ko;
  if (lane < 32) {
    qo = qv * cs + qp * sn;
    ko = kv * cs + kp * sn;
  } else {
    qo = qv * cs - qp * sn;
    ko = kv * cs - kp * sn;
  }
  qh[base] = f2bf(qo);
  kh[base] = f2bf(ko);
}

// ---------------- chunked sliding-window attention ----------------
// block = (n,h,c): 4 waves x 32 q-rows; keys = 256 (prev chunk + cur chunk)
__global__ __launch_bounds__(256) void k_attn(const unsigned short* __restrict__ qh,
                                              const unsigned short* __restrict__ kh,
                                              const unsigned short* __restrict__ vh,
                                              unsigned short* __restrict__ ao) {
  extern __shared__ __align__(16) char lds[];
  unsigned short* Vt = (unsigned short*)lds;                    // [64][264]
  unsigned short* Pb = (unsigned short*)(lds + 64 * 264 * 2);   // 4 x [32][72]
  const int b = blockIdx.x;
  const int c = b & 31, nh = b >> 5;  // nh = n*16+h
  const int tid = threadIdx.x, lane = tid & 63, w = tid >> 6;
  const int lrow = lane & 15, g = lane >> 4, lk8 = g * 8;
  const size_t hb = (size_t)nh * T_S * 64;
  const unsigned short* qg = qh + hb + (size_t)c * 128 * 64;
  const unsigned short* kg = kh + hb + ((ptrdiff_t)c * 128 - 128) * 64;
  const unsigned short* vg = vh + hb + ((ptrdiff_t)c * 128 - 128) * 64;

  // stage V transposed: Vt[d][m], stride 264 (16B-aligned rows, bank-uniform)
#pragma unroll
  for (int it = 0; it < 8; ++it) {
    int chunk = tid + it * 256;  // 0..2047
    int m = chunk >> 3, d0 = (chunk & 7) * 8;
    short8 v = {0, 0, 0, 0, 0, 0, 0, 0};
    if (!(c == 0 && m < 128)) v = *(const short8*)(vg + (size_t)m * 64 + d0);
#pragma unroll
    for (int j = 0; j < 8; ++j) Vt[(d0 + j) * 264 + m] = (unsigned short)v[j];
  }

  // Q fragments (rows w*32..w*32+31), straight from global
  bf16x8 qf[2][2];
#pragma unroll
  for (int mi = 0; mi < 2; ++mi)
#pragma unroll
    for (int ks = 0; ks < 2; ++ks)
      qf[mi][ks] =
          *(const bf16x8*)(qg + (size_t)(w * 32 + mi * 16 + lrow) * 64 + ks * 32 + lk8);

  // S = Q K^T  (C/D layout: col=key=lane&15, row=q=(lane>>4)*4+reg)
  f32x4 s[2][16] = {};
#pragma unroll
  for (int ni = 0; ni < 16; ++ni) {
    if (c == 0 && ni < 8) continue;  // masked & would be OOB
    bf16x8 kf0 = *(const bf16x8*)(kg + (size_t)(ni * 16 + lrow) * 64 + lk8);
    bf16x8 kf1 = *(const bf16x8*)(kg + (size_t)(ni * 16 + lrow) * 64 + 32 + lk8);
#pragma unroll
    for (int mi = 0; mi < 2; ++mi) {
      s[mi][ni] = mfma16(qf[mi][0], kf0, s[mi][ni]);
      s[mi][ni] = mfma16(qf[mi][1], kf1, s[mi][ni]);
    }
  }

  // mask + scale + row softmax (row = 16 lanes x 16 ni-regs)
#pragma unroll
  for (int mi = 0; mi < 2; ++mi) {
#pragma unroll
    for (int j = 0; j < 4; ++j) {
      int jq = w * 32 + mi * 16 + g * 4 + j;
      float mx = -1e30f;
#pragma unroll
      for (int ni = 0; ni < 16; ++ni) {
        int m = ni * 16 + lrow;
        bool ok = (m > jq) && (m <= 128 + jq) && (c > 0 || m >= 128);
        float val = ok ? s[mi][ni][j] * 0.125f : -1e30f;
        s[mi][ni][j] = val;
        mx = fmaxf(mx, val);
      }
#pragma unroll
      for (int d2 = 1; d2 < 16; d2 <<= 1) mx = fmaxf(mx, __shfl_xor(mx, d2, 64));
      float sum = 0.0f;
#pragma unroll
      for (int ni = 0; ni < 16; ++ni) {
        float p = __expf(s[mi][ni][j] - mx);
        s[mi][ni][j] = p;
        sum += p;
      }
#pragma unroll
      for (int d2 = 1; d2 < 16; d2 <<= 1) sum += __shfl_xor(sum, d2, 64);
      float inv = 1.0f / sum;
#pragma unroll
      for (int ni = 0; ni < 16; ++ni) s[mi][ni][j] *= inv;
    }
  }

  __syncthreads();  // Vt fully staged before PV reads

  // PV in 64-key quarters; P staged per-wave in LDS (stride 72)
  f32x4 oacc[2][4] = {};
  unsigned short* Pw = Pb + w * (32 * 72);
#pragma unroll
  for (int qi = 0; qi < 4; ++qi) {
#pragma unroll
    for (int mi = 0; mi < 2; ++mi)
#pragma unroll
      for (int ni4 = 0; ni4 < 4; ++ni4) {
        int ni = qi * 4 + ni4;
#pragma unroll
        for (int j = 0; j < 4; ++j) {
          int r = mi * 16 + g * 4 + j;
          Pw[r * 72 + ni4 * 16 + lrow] = f2bf(s[mi][ni][j]);
        }
      }
    // per-wave private region: lgkmcnt ordering suffices (no cross-wave barrier)
#pragma unroll
    for (int ks = 0; ks < 2; ++ks) {
      bf16x8 pf[2], vf[4];
#pragma unroll
      for (int mi = 0; mi < 2; ++mi)
        pf[mi] = *(const bf16x8*)&Pw[(mi * 16 + lrow) * 72 + ks * 32 + lk8];
#pragma unroll
      for (int nj = 0; nj < 4; ++nj)
        vf[nj] = *(const bf16x8*)&Vt[(nj * 16 + lrow) * 264 + qi * 64 + ks * 32 + lk8];
#pragma unroll
      for (int mi = 0; mi < 2; ++mi)
#pragma unroll
        for (int nj = 0; nj < 4; ++nj)
          oacc[mi][nj] = mfma16(pf[mi], vf[nj], oacc[mi][nj]);
    }
  }

  // write attention out, token-major [n*T+t][h*64+d] bf16
  const int t0 = c * 128 + w * 32;
  const int n_ = nh >> 4, h_ = nh & 15;
#pragma unroll
  for (int mi = 0; mi < 2; ++mi)
#pragma unroll
    for (int nj = 0; nj < 4; ++nj)
#pragma unroll
      for (int j = 0; j < 4; ++j) {
        int t = t0 + mi * 16 + g * 4 + j;
        int dcol = nj * 16 + lrow;
        ao[((size_t)n_ * T_S + t) * D_M + h_ * 64 + dcol] = f2bf(oacc[mi][nj][j]);
      }
}

extern "C" void kernel_launch(void* const* d_in, const int* in_sizes, int n_in,
                              void* d_out, int out_size, void* d_ws, size_t ws_size,
                              hipStream_t stream) {
  const float* x = (const float*)d_in[0];      // [2,4096,1024]
  const float* qkvw = (const float*)d_in[1];   // [3,1024,1024]
  const float* ow = (const float*)d_in[2];     // [1024,1024]
  const float* osc = (const float*)d_in[3];    // [1024]
  float* out = (float*)d_out;

  char* ws = (char*)d_ws;
  unsigned short* xn = (unsigned short*)(ws + 0);            // 16,777,216
  unsigned short* qkvwb = (unsigned short*)(ws + 16777216);  //  6,291,456
  unsigned short* owb = (unsigned short*)(ws + 23068672);    //  2,097,152
  unsigned short* qhb = (unsigned short*)(ws + 25165824);    // 16,777,216
  unsigned short* khb = (unsigned short*)(ws + 41943040);    // 16,777,216
  unsigned short* vhb = (unsigned short*)(ws + 58720256);    // 16,777,216
  unsigned short* aob = (unsigned short*)(ws + 75497472);    // 16,777,216
  float* cosT = (float*)(ws + 92274688);                     //    524,288
  float* sinT = (float*)(ws + 92798976);                     //    524,288

  k_rope_tab<<<512, 256, 0, stream>>>(cosT, sinT);
  k_f32_to_bf16<<<3072, 256, 0, stream>>>(qkvw, qkvwb);
  k_f32_to_bf16<<<1024, 256, 0, stream>>>(ow, owb);
  k_rmsnorm_cast<<<8192, 256, 0, stream>>>(x, xn);
  k_gemm256<0><<<dim3(24, 32), 512, 73728, stream>>>(xn, qkvwb, qhb, khb, vhb, nullptr,
                                                     nullptr, nullptr, 8192, 3072, 1024);
  k_rope_qk<<<32768, 256, 0, stream>>>(qhb, khb, cosT, sinT);
  k_attn<<<1024, 256, 52224, stream>>>(qhb, khb, vhb, aob);
  k_gemm256<1><<<dim3(8, 32), 512, 73728, stream>>>(aob, owb, nullptr, nullptr, nullptr,
                                                    out, x, osc, 8192, 1024, 1024);
}

// Round 3
// 175.214 us; speedup vs baseline: 1.1882x; 1.0766x over previous
//
#include <hip/hip_runtime.h>
#include <hip/hip_bf16.h>
#include <stdint.h>
#include <stddef.h>

#define T_S 4096
#define D_M 1024
#define NH_ 16
#define EPSF 1.1920929e-07f

typedef float f32x4 __attribute__((ext_vector_type(4)));
typedef __bf16 bf16x8 __attribute__((ext_vector_type(8)));
typedef short short8 __attribute__((ext_vector_type(8)));
typedef unsigned short ushort4v __attribute__((ext_vector_type(4)));

static __device__ __forceinline__ unsigned short f2bf(float f) {
  unsigned int u = __builtin_bit_cast(unsigned int, f);
  unsigned int r = (u + 0x7fffu + ((u >> 16) & 1u)) >> 16;
  return (unsigned short)r;
}
static __device__ __forceinline__ float bf2f(unsigned short s) {
  unsigned int u = ((unsigned int)s) << 16;
  return __builtin_bit_cast(float, u);
}

#define GLDS16(gp, lp) __builtin_amdgcn_global_load_lds( \
    (__attribute__((address_space(1))) void*)(gp),       \
    (__attribute__((address_space(3))) void*)(lp), 16, 0, 0)

static __device__ __forceinline__ f32x4 mfma16(bf16x8 a, bf16x8 b, f32x4 c) {
  return __builtin_amdgcn_mfma_f32_16x16x32_bf16(a, b, c, 0, 0, 0);
}

// ---------------- RoPE cos/sin table: [T][32] ----------------
__global__ __launch_bounds__(256) void k_rope_tab(float* __restrict__ cosT,
                                                  float* __restrict__ sinT) {
  int i = blockIdx.x * 256 + threadIdx.x;  // t*32 + f
  int t = i >> 5, f = i & 31;
  float fr = (f < 16) ? powf(1e-4f, (float)f * (1.0f / 15.0f)) : 0.0f;
  float th = (float)t * fr;
  cosT[i] = cosf(th);
  sinT[i] = sinf(th);
}

// ---------------- f32 -> bf16 ----------------
__global__ __launch_bounds__(256) void k_f32_to_bf16(const float* __restrict__ src,
                                                     unsigned short* __restrict__ dst) {
  int i = blockIdx.x * 256 + threadIdx.x;
  float4 v = ((const float4*)src)[i];
  ushort4v o;
  o.x = f2bf(v.x); o.y = f2bf(v.y); o.z = f2bf(v.z); o.w = f2bf(v.w);
  ((ushort4v*)dst)[i] = o;
}

// ---------------- RMSNorm over D=1024 + cast ----------------
__global__ __launch_bounds__(256) void k_rmsnorm_cast(const float* __restrict__ x,
                                                      unsigned short* __restrict__ xn) {
  const int row = blockIdx.x;
  const int tid = threadIdx.x;
  float4 v = ((const float4*)(x + (size_t)row * D_M))[tid];
  float ss = v.x * v.x + v.y * v.y + v.z * v.z + v.w * v.w;
#pragma unroll
  for (int d = 1; d < 64; d <<= 1) ss += __shfl_xor(ss, d, 64);
  __shared__ float red[4];
  if ((tid & 63) == 0) red[tid >> 6] = ss;
  __syncthreads();
  float sc = rsqrtf((red[0] + red[1] + red[2] + red[3]) * (1.0f / D_M) + EPSF);
  ushort4v o;
  o.x = f2bf(v.x * sc); o.y = f2bf(v.y * sc); o.z = f2bf(v.z * sc); o.w = f2bf(v.w * sc);
  ((ushort4v*)(xn + (size_t)row * D_M))[tid] = o;
}

// ---------------- bf16 GEMM, C = A @ B^T, 8-phase schedule ----------------
// BM=BN=128, BK=64, 4 waves (2Mx2N), wave tile 64x64, 2 LDS dbuf x 32KB.
// Per K-tile: 4 phases (kh,nh); per phase: 6 ds_read_b128 + stage 1 half
// (2 global_load_lds) + 8 MFMA between two barriers. vmcnt(6) at even phases
// (steady state; every staged half is >=5 phases before its first read, and
// is outside the 3-half window at its covering wait). Tail iter: vmcnt(0).
// K fixed at 1024 (NT=16 tiles, 8 iters).
// EPI 0: fused per-head RMSNorm+RoPE scatter -> q/k/v head-major bf16
// EPI 1: Cf = resid + scale[col]*acc (f32)
#define VMW do { if (tail) asm volatile("s_waitcnt vmcnt(0)" ::: "memory"); \
                 else asm volatile("s_waitcnt vmcnt(6)" ::: "memory"); } while (0)

#define PHASE(CD, KH, NH, STG, DOVM) do {                                        \
    bf16x8 aF[4], bF[2];                                                         \
    _Pragma("unroll") for (int mi = 0; mi < 4; ++mi) {                           \
      int r = wm * 64 + mi * 16 + lrow;                                          \
      aF[mi] = *(const bf16x8*)(lds + (CD) * 32768 + (KH) * 8192 + r * 64 +      \
                                ((g4 ^ ((r >> 1) & 3)) << 4));                   \
    }                                                                            \
    _Pragma("unroll") for (int b = 0; b < 2; ++b) {                              \
      int r = wn * 64 + ((NH) * 2 + b) * 16 + lrow;                              \
      bF[b] = *(const bf16x8*)(lds + (CD) * 32768 + 16384 + (KH) * 8192 +        \
                               r * 64 + ((g4 ^ ((r >> 1) & 3)) << 4));           \
    }                                                                            \
    STG;                                                                         \
    if (DOVM) VMW;                                                               \
    __builtin_amdgcn_s_barrier();                                                \
    asm volatile("" ::: "memory");                                               \
    __builtin_amdgcn_s_setprio(1);                                               \
    _Pragma("unroll") for (int mi = 0; mi < 4; ++mi) {                           \
      acc[mi][(NH) * 2 + 0] = mfma16(aF[mi], bF[0], acc[mi][(NH) * 2 + 0]);      \
      acc[mi][(NH) * 2 + 1] = mfma16(aF[mi], bF[1], acc[mi][(NH) * 2 + 1]);      \
    }                                                                            \
    __builtin_amdgcn_s_setprio(0);                                               \
    asm volatile("" ::: "memory");                                               \
    __builtin_amdgcn_s_barrier();                                                \
    asm volatile("" ::: "memory");                                               \
  } while (0)

template <int EPI>
__global__ __launch_bounds__(256, 2) void k_gemm8p(
    const unsigned short* __restrict__ Ag, const unsigned short* __restrict__ Bg,
    unsigned short* __restrict__ q_out, unsigned short* __restrict__ k_out,
    unsigned short* __restrict__ v_out, float* __restrict__ Cf,
    const float* __restrict__ resid, const float* __restrict__ scale,
    const float* __restrict__ cosT, const float* __restrict__ sinT,
    int gx, int cpx) {
  extern __shared__ __align__(16) char lds[];  // 2 x 32768
  const int tid = threadIdx.x;
  const int lane = tid & 63, w = tid >> 6;
  const int lrow = lane & 15, g4 = lane >> 4;
  const int wm = w >> 1, wn = w & 1;
  // bijective XCD swizzle (grid % 8 == 0)
  const int id = (blockIdx.x & 7) * cpx + (blockIdx.x >> 3);
  const int m0 = (id / gx) * 128, n0 = (id % gx) * 128;

  const int gs8 = (((tid & 3) ^ ((tid >> 3) & 3)) << 3);
  const int r0s = tid >> 2;

  auto sA = [&](int t, int kh, int db) {
    const unsigned short* s = Ag + (size_t)(m0 + r0s) * 1024 + t * 64 + kh * 32 + gs8;
    char* d = lds + db * 32768 + kh * 8192 + tid * 16;
    GLDS16(s, d);
    GLDS16(s + 64 * 1024, d + 4096);
  };
  auto sB = [&](int t, int kh, int db) {
    const unsigned short* s = Bg + (size_t)(n0 + r0s) * 1024 + t * 64 + kh * 32 + gs8;
    char* d = lds + db * 32768 + 16384 + kh * 8192 + tid * 16;
    GLDS16(s, d);
    GLDS16(s + 64 * 1024, d + 4096);
  };

  f32x4 acc[4][4] = {};

  // prologue: t0 {A0,B0,A1,B1}->dbuf0, t1 {A0,B0}->dbuf1
  sA(0, 0, 0); sB(0, 0, 0); sA(0, 1, 0); sB(0, 1, 0); sA(1, 0, 1); sB(1, 0, 1);
  asm volatile("s_waitcnt vmcnt(4)" ::: "memory");
  __builtin_amdgcn_s_barrier();
  asm volatile("" ::: "memory");

  for (int i = 0; i < 8; ++i) {
    const int t1 = 2 * i + 1, t2 = 2 * i + 2, t3 = 2 * i + 3;
    const bool tail = (t2 >= 16);
    PHASE(0, 0, 0, { sA(t1, 1, 1); }, 0);
    PHASE(0, 0, 1, { sB(t1, 1, 1); }, 1);
    PHASE(0, 1, 0, { if (!tail) sA(t2, 0, 0); }, 0);
    PHASE(0, 1, 1, { if (!tail) sB(t2, 0, 0); }, 1);
    PHASE(1, 0, 0, { if (!tail) sA(t2, 1, 0); }, 0);
    PHASE(1, 0, 1, { if (!tail) sB(t2, 1, 0); }, 1);
    PHASE(1, 1, 0, { if (t3 < 16) sA(t3, 0, 1); }, 0);
    PHASE(1, 1, 1, { if (t3 < 16) sB(t3, 0, 1); }, 1);
  }

  const int rbase = m0 + wm * 64 + g4 * 4;  // + mi*16 + j
  const int colbase = n0 + wn * 64;         // wave covers exactly one head (64 cols)

  if (EPI == 1) {
#pragma unroll
    for (int mi = 0; mi < 4; ++mi)
#pragma unroll
      for (int nf = 0; nf < 4; ++nf) {
        int col = colbase + nf * 16 + lrow;
        float sc = scale[col];
#pragma unroll
        for (int j = 0; j < 4; ++j) {
          int row = rbase + mi * 16 + j;
          size_t idx = (size_t)row * 1024 + col;
          Cf[idx] = resid[idx] + sc * acc[mi][nf][j];
        }
      }
  } else {
    const int which = colbase >> 10;
    const int hh = (colbase >> 6) & 15;
    if (which == 2) {
#pragma unroll
      for (int mi = 0; mi < 4; ++mi)
#pragma unroll
        for (int j = 0; j < 4; ++j) {
          int row = rbase + mi * 16 + j;
          int t = row & (T_S - 1), nn = row >> 12;
          size_t ob = ((size_t)(nn * NH_ + hh) * T_S + t) * 64;
#pragma unroll
          for (int nf = 0; nf < 4; ++nf)
            v_out[ob + nf * 16 + lrow] = f2bf(acc[mi][nf][j]);
        }
    } else {
      unsigned short* dst = which ? k_out : q_out;
#pragma unroll
      for (int mi = 0; mi < 4; ++mi)
#pragma unroll
        for (int j = 0; j < 4; ++j) {
          int row = rbase + mi * 16 + j;
          int t = row & (T_S - 1), nn = row >> 12;
          float ss = 0.0f;
#pragma unroll
          for (int nf = 0; nf < 4; ++nf) ss += acc[mi][nf][j] * acc[mi][nf][j];
          ss += __shfl_xor(ss, 1, 64);
          ss += __shfl_xor(ss, 2, 64);
          ss += __shfl_xor(ss, 4, 64);
          ss += __shfl_xor(ss, 8, 64);
          float sc = rsqrtf(ss * (1.0f / 64.0f) + EPSF);
          size_t ob = ((size_t)(nn * NH_ + hh) * T_S + t) * 64;
#pragma unroll
          for (int nf = 0; nf < 2; ++nf) {
            int dd = nf * 16 + lrow;
            float cs = cosT[t * 32 + dd], sn = sinT[t * 32 + dd];
            float z1 = acc[mi][nf][j] * sc, z2 = acc[mi][nf + 2][j] * sc;
            dst[ob + dd] = f2bf(z1 * cs + z2 * sn);
            dst[ob + dd + 32] = f2bf(z2 * cs - z1 * sn);
          }
        }
    }
  }
}

// ---------------- chunked sliding-window attention ----------------
__global__ __launch_bounds__(256) void k_attn(const unsigned short* __restrict__ qh,
                                              const unsigned short* __restrict__ kh,
                                              const unsigned short* __restrict__ vh,
                                              unsigned short* __restrict__ ao) {
  extern __shared__ __align__(16) char lds[];
  unsigned short* Vt = (unsigned short*)lds;                    // [64][264]
  unsigned short* Pb = (unsigned short*)(lds + 64 * 264 * 2);   // 4 x [32][72]
  const int b = blockIdx.x;
  const int c = b & 31, nh = b >> 5;  // nh = n*16+h
  const int tid = threadIdx.x, lane = tid & 63, w = tid >> 6;
  const int lrow = lane & 15, g = lane >> 4, lk8 = g * 8;
  const size_t hb = (size_t)nh * T_S * 64;
  const unsigned short* qg = qh + hb + (size_t)c * 128 * 64;
  const unsigned short* kg = kh + hb + ((ptrdiff_t)c * 128 - 128) * 64;
  const unsigned short* vg = vh + hb + ((ptrdiff_t)c * 128 - 128) * 64;

  // stage V transposed via register 8x8 transpose, b128 writes
  {
    const int m_idx = (tid & 7) | ((tid >> 6) << 3);  // 0..31
    const int m0v = m_idx * 8;
    const int d0 = ((tid >> 3) & 7) * 8;
    short8 vv[8];
#pragma unroll
    for (int i = 0; i < 8; ++i) {
      short8 z = {0, 0, 0, 0, 0, 0, 0, 0};
      if (!(c == 0 && m0v < 128)) z = *(const short8*)(vg + (size_t)(m0v + i) * 64 + d0);
      vv[i] = z;
    }
#pragma unroll
    for (int jj = 0; jj < 8; ++jj) {
      short8 wv;
#pragma unroll
      for (int i = 0; i < 8; ++i) wv[i] = vv[i][jj];
      *(short8*)(Vt + (size_t)(d0 + jj) * 264 + m0v) = wv;
    }
  }

  // Q fragments (rows w*32..w*32+31)
  bf16x8 qf[2][2];
#pragma unroll
  for (int mi = 0; mi < 2; ++mi)
#pragma unroll
    for (int ks = 0; ks < 2; ++ks)
      qf[mi][ks] =
          *(const bf16x8*)(qg + (size_t)(w * 32 + mi * 16 + lrow) * 64 + ks * 32 + lk8);

  // S = Q K^T
  f32x4 s[2][16] = {};
#pragma unroll
  for (int ni = 0; ni < 16; ++ni) {
    if (c == 0 && ni < 8) continue;
    bf16x8 kf0 = *(const bf16x8*)(kg + (size_t)(ni * 16 + lrow) * 64 + lk8);
    bf16x8 kf1 = *(const bf16x8*)(kg + (size_t)(ni * 16 + lrow) * 64 + 32 + lk8);
#pragma unroll
    for (int mi = 0; mi < 2; ++mi) {
      s[mi][ni] = mfma16(qf[mi][0], kf0, s[mi][ni]);
      s[mi][ni] = mfma16(qf[mi][1], kf1, s[mi][ni]);
    }
  }

  // mask + scale + row softmax
#pragma unroll
  for (int mi = 0; mi < 2; ++mi) {
#pragma unroll
    for (int j = 0; j < 4; ++j) {
      int jq = w * 32 + mi * 16 + g * 4 + j;
      float mx = -1e30f;
#pragma unroll
      for (int ni = 0; ni < 16; ++ni) {
        int m = ni * 16 + lrow;
        bool ok = (m > jq) && (m <= 128 + jq) && (c > 0 || m >= 128);
        float val = ok ? s[mi][ni][j] * 0.125f : -1e30f;
        s[mi][ni][j] = val;
        mx = fmaxf(mx, val);
      }
#pragma unroll
      for (int d2 = 1; d2 < 16; d2 <<= 1) mx = fmaxf(mx, __shfl_xor(mx, d2, 64));
      float sum = 0.0f;
#pragma unroll
      for (int ni = 0; ni < 16; ++ni) {
        float p = __expf(s[mi][ni][j] - mx);
        s[mi][ni][j] = p;
        sum += p;
      }
#pragma unroll
      for (int d2 = 1; d2 < 16; d2 <<= 1) sum += __shfl_xor(sum, d2, 64);
      float inv = 1.0f / sum;
#pragma unroll
      for (int ni = 0; ni < 16; ++ni) s[mi][ni][j] *= inv;
    }
  }

  __syncthreads();  // Vt staged before PV reads

  // PV in 64-key quarters; P staged per-wave in LDS (stride 72)
  f32x4 oacc[2][4] = {};
  unsigned short* Pw = Pb + w * (32 * 72);
#pragma unroll
  for (int qi = 0; qi < 4; ++qi) {
#pragma unroll
    for (int mi = 0; mi < 2; ++mi)
#pragma unroll
      for (int ni4 = 0; ni4 < 4; ++ni4) {
        int ni = qi * 4 + ni4;
#pragma unroll
        for (int j = 0; j < 4; ++j) {
          int r = mi * 16 + g * 4 + j;
          Pw[r * 72 + ni4 * 16 + lrow] = f2bf(s[mi][ni][j]);
        }
      }
#pragma unroll
    for (int ks = 0; ks < 2; ++ks) {
      bf16x8 pf[2], vf[4];
#pragma unroll
      for (int mi = 0; mi < 2; ++mi)
        pf[mi] = *(const bf16x8*)&Pw[(mi * 16 + lrow) * 72 + ks * 32 + lk8];
#pragma unroll
      for (int nj = 0; nj < 4; ++nj)
        vf[nj] = *(const bf16x8*)&Vt[(nj * 16 + lrow) * 264 + qi * 64 + ks * 32 + lk8];
#pragma unroll
      for (int mi = 0; mi < 2; ++mi)
#pragma unroll
        for (int nj = 0; nj < 4; ++nj)
          oacc[mi][nj] = mfma16(pf[mi], vf[nj], oacc[mi][nj]);
    }
  }

  const int t0 = c * 128 + w * 32;
  const int n_ = nh >> 4, h_ = nh & 15;
#pragma unroll
  for (int mi = 0; mi < 2; ++mi)
#pragma unroll
    for (int nj = 0; nj < 4; ++nj)
#pragma unroll
      for (int j = 0; j < 4; ++j) {
        int t = t0 + mi * 16 + g * 4 + j;
        int dcol = nj * 16 + lrow;
        ao[((size_t)n_ * T_S + t) * D_M + h_ * 64 + dcol] = f2bf(oacc[mi][nj][j]);
      }
}

extern "C" void kernel_launch(void* const* d_in, const int* in_sizes, int n_in,
                              void* d_out, int out_size, void* d_ws, size_t ws_size,
                              hipStream_t stream) {
  const float* x = (const float*)d_in[0];      // [2,4096,1024]
  const float* qkvw = (const float*)d_in[1];   // [3,1024,1024]
  const float* ow = (const float*)d_in[2];     // [1024,1024]
  const float* osc = (const float*)d_in[3];    // [1024]
  float* out = (float*)d_out;

  char* ws = (char*)d_ws;
  unsigned short* xn = (unsigned short*)(ws + 0);            // 16,777,216
  unsigned short* qkvwb = (unsigned short*)(ws + 16777216);  //  6,291,456
  unsigned short* owb = (unsigned short*)(ws + 23068672);    //  2,097,152
  unsigned short* qhb = (unsigned short*)(ws + 25165824);    // 16,777,216
  unsigned short* khb = (unsigned short*)(ws + 41943040);    // 16,777,216
  unsigned short* vhb = (unsigned short*)(ws + 58720256);    // 16,777,216
  unsigned short* aob = (unsigned short*)(ws + 75497472);    // 16,777,216
  float* cosT = (float*)(ws + 92274688);                     //    524,288
  float* sinT = (float*)(ws + 92798976);                     //    524,288

  k_rope_tab<<<512, 256, 0, stream>>>(cosT, sinT);
  k_f32_to_bf16<<<3072, 256, 0, stream>>>(qkvw, qkvwb);
  k_f32_to_bf16<<<1024, 256, 0, stream>>>(ow, owb);
  k_rmsnorm_cast<<<8192, 256, 0, stream>>>(x, xn);
  // QKV: M=8192, N=3072 -> grid 64*24 = 1536 (3 exact rounds at 2 blocks/CU)
  k_gemm8p<0><<<1536, 256, 65536, stream>>>(xn, qkvwb, qhb, khb, vhb, nullptr,
                                            nullptr, nullptr, cosT, sinT, 24, 192);
  k_attn<<<1024, 256, 52224, stream>>>(qhb, khb, vhb, aob);
  // O-proj: M=8192, N=1024 -> grid 64*8 = 512 (1 exact round)
  k_gemm8p<1><<<512, 256, 65536, stream>>>(aob, owb, nullptr, nullptr, nullptr, out,
                                           x, osc, nullptr, nullptr, 8, 64);
}

// Round 4
// 145.844 us; speedup vs baseline: 1.4274x; 1.2014x over previous
//
#include <hip/hip_runtime.h>
#include <hip/hip_bf16.h>
#include <stdint.h>
#include <stddef.h>

#define T_S 4096
#define D_M 1024
#define NH_ 16
#define EPSF 1.1920929e-07f

typedef float f32x4 __attribute__((ext_vector_type(4)));
typedef __bf16 bf16x8 __attribute__((ext_vector_type(8)));
typedef short short8 __attribute__((ext_vector_type(8)));
typedef unsigned short ushort4v __attribute__((ext_vector_type(4)));

static __device__ __forceinline__ unsigned short f2bf(float f) {
  unsigned int u = __builtin_bit_cast(unsigned int, f);
  unsigned int r = (u + 0x7fffu + ((u >> 16) & 1u)) >> 16;
  return (unsigned short)r;
}

#define GLDS16(gp, lp) __builtin_amdgcn_global_load_lds( \
    (__attribute__((address_space(1))) void*)(gp),       \
    (__attribute__((address_space(3))) void*)(lp), 16, 0, 0)

static __device__ __forceinline__ f32x4 mfma16(bf16x8 a, bf16x8 b, f32x4 c) {
  return __builtin_amdgcn_mfma_f32_16x16x32_bf16(a, b, c, 0, 0, 0);
}

// ---------------- RoPE cos/sin table: [T][32] ----------------
__global__ __launch_bounds__(256) void k_rope_tab(float* __restrict__ cosT,
                                                  float* __restrict__ sinT) {
  int i = blockIdx.x * 256 + threadIdx.x;  // t*32 + f
  int t = i >> 5, f = i & 31;
  float fr = (f < 16) ? powf(1e-4f, (float)f * (1.0f / 15.0f)) : 0.0f;
  float th = (float)t * fr;
  cosT[i] = cosf(th);
  sinT[i] = sinf(th);
}

// ---------------- f32 -> bf16 ----------------
__global__ __launch_bounds__(256) void k_f32_to_bf16(const float* __restrict__ src,
                                                     unsigned short* __restrict__ dst) {
  int i = blockIdx.x * 256 + threadIdx.x;
  float4 v = ((const float4*)src)[i];
  ushort4v o;
  o.x = f2bf(v.x); o.y = f2bf(v.y); o.z = f2bf(v.z); o.w = f2bf(v.w);
  ((ushort4v*)dst)[i] = o;
}

// ---------------- RMSNorm over D=1024 + cast ----------------
__global__ __launch_bounds__(256) void k_rmsnorm_cast(const float* __restrict__ x,
                                                      unsigned short* __restrict__ xn) {
  const int row = blockIdx.x;
  const int tid = threadIdx.x;
  float4 v = ((const float4*)(x + (size_t)row * D_M))[tid];
  float ss = v.x * v.x + v.y * v.y + v.z * v.z + v.w * v.w;
#pragma unroll
  for (int d = 1; d < 64; d <<= 1) ss += __shfl_xor(ss, d, 64);
  __shared__ float red[4];
  if ((tid & 63) == 0) red[tid >> 6] = ss;
  __syncthreads();
  float sc = rsqrtf((red[0] + red[1] + red[2] + red[3]) * (1.0f / D_M) + EPSF);
  ushort4v o;
  o.x = f2bf(v.x * sc); o.y = f2bf(v.y * sc); o.z = f2bf(v.z * sc); o.w = f2bf(v.w * sc);
  ((ushort4v*)(xn + (size_t)row * D_M))[tid] = o;
}

// ---------------- bf16 GEMM, C = A @ B^T, 3-stage pipeline (R2-proven) ----------------
// BM=256, BN=128, BK=32; 8 waves (4M x 2N), wave tile 64x64; 3 LDS buffers.
// EPI 0: fused per-head RMSNorm+RoPE scatter -> q/k/v head-major bf16 [n,h,t,d]
// EPI 1: Cf = resid + scale[col]*acc (f32)
template <int EPI>
__global__ __launch_bounds__(512) void k_gemm256(
    const unsigned short* __restrict__ A, const unsigned short* __restrict__ B,
    unsigned short* __restrict__ q_out, unsigned short* __restrict__ k_out,
    unsigned short* __restrict__ v_out, float* __restrict__ Cf,
    const float* __restrict__ resid, const float* __restrict__ scale,
    const float* __restrict__ cosT, const float* __restrict__ sinT,
    int M, int Ncols, int K) {
  extern __shared__ __align__(16) char lds[];  // 3 x (16384 A + 8192 B) = 73728 B
  const int tid = threadIdx.x;
  const int lane = tid & 63, w = tid >> 6;
  const int lrow = lane & 15, g = lane >> 4;
  const int wm = w >> 1, wn = w & 1;
  const int m0 = blockIdx.y * 256, n0 = blockIdx.x * 128;
  const int NT = K >> 5;

  const int srcgrp = (((tid & 3) ^ ((tid >> 3) & 3)) << 3);
  const size_t aoff0 = (size_t)(m0 + (tid >> 2)) * K + srcgrp;
  const size_t aoff1 = aoff0 + (size_t)128 * K;
  const size_t boff = (size_t)(n0 + (tid >> 2)) * K + srcgrp;
  const int wbase = w * 1024;

  int abyte[4], bbyte[4];
#pragma unroll
  for (int i = 0; i < 4; ++i) {
    int ar = wm * 64 + i * 16 + lrow;
    abyte[i] = ar * 64 + ((g ^ ((ar >> 1) & 3)) << 4);
    int br = wn * 64 + i * 16 + lrow;
    bbyte[i] = 16384 + br * 64 + ((g ^ ((br >> 1) & 3)) << 4);
  }

  f32x4 acc[4][4] = {};

#pragma unroll
  for (int t = 0; t < 2; ++t) {
    char* sp = lds + t * 24576;
    GLDS16(A + aoff0 + t * 32, sp + wbase);
    GLDS16(A + aoff1 + t * 32, sp + 8192 + wbase);
    GLDS16(B + boff + t * 32, sp + 16384 + wbase);
  }
  asm volatile("s_waitcnt vmcnt(3)" ::: "memory");
  __builtin_amdgcn_s_barrier();
  asm volatile("" ::: "memory");

  int cb = 0, sb = 49152;
  for (int t = 0; t < NT; ++t) {
    if (t + 2 < NT) {
      const int kt2 = (t + 2) << 5;
      char* sp = lds + sb;
      GLDS16(A + aoff0 + kt2, sp + wbase);
      GLDS16(A + aoff1 + kt2, sp + 8192 + wbase);
      GLDS16(B + boff + kt2, sp + 16384 + wbase);
    }
    const char* cp = lds + cb;
    bf16x8 aF[4], bF[4];
#pragma unroll
    for (int i = 0; i < 4; ++i) aF[i] = *(const bf16x8*)(cp + abyte[i]);
#pragma unroll
    for (int i = 0; i < 4; ++i) bF[i] = *(const bf16x8*)(cp + bbyte[i]);
    __builtin_amdgcn_s_setprio(1);
#pragma unroll
    for (int mi = 0; mi < 4; ++mi)
#pragma unroll
      for (int ni = 0; ni < 4; ++ni)
        acc[mi][ni] = mfma16(aF[mi], bF[ni], acc[mi][ni]);
    __builtin_amdgcn_s_setprio(0);
    if (t + 2 < NT)
      asm volatile("s_waitcnt vmcnt(3)" ::: "memory");
    else
      asm volatile("s_waitcnt vmcnt(0)" ::: "memory");
    __builtin_amdgcn_s_barrier();
    asm volatile("" ::: "memory");
    cb += 24576; if (cb == 73728) cb = 0;
    sb += 24576; if (sb == 73728) sb = 0;
  }

  const int rbase = m0 + wm * 64 + g * 4;  // + mi*16 + j
  const int colbase = n0 + wn * 64;        // wave covers exactly one head

  if (EPI == 1) {
#pragma unroll
    for (int mi = 0; mi < 4; ++mi)
#pragma unroll
      for (int nf = 0; nf < 4; ++nf) {
        int col = colbase + nf * 16 + lrow;
        float sc = scale[col];
#pragma unroll
        for (int j = 0; j < 4; ++j) {
          int row = rbase + mi * 16 + j;
          size_t idx = (size_t)row * Ncols + col;
          Cf[idx] = resid[idx] + sc * acc[mi][nf][j];
        }
      }
  } else {
    const int which = colbase >> 10;
    const int hh = (colbase >> 6) & 15;
    if (which == 2) {
#pragma unroll
      for (int mi = 0; mi < 4; ++mi)
#pragma unroll
        for (int j = 0; j < 4; ++j) {
          int row = rbase + mi * 16 + j;
          int t = row & (T_S - 1), nn = row >> 12;
          size_t ob = ((size_t)(nn * NH_ + hh) * T_S + t) * 64;
#pragma unroll
          for (int nf = 0; nf < 4; ++nf)
            v_out[ob + nf * 16 + lrow] = f2bf(acc[mi][nf][j]);
        }
    } else {
      unsigned short* dst = which ? k_out : q_out;
#pragma unroll
      for (int mi = 0; mi < 4; ++mi)
#pragma unroll
        for (int j = 0; j < 4; ++j) {
          int row = rbase + mi * 16 + j;
          int t = row & (T_S - 1), nn = row >> 12;
          float ss = 0.0f;
#pragma unroll
          for (int nf = 0; nf < 4; ++nf) ss += acc[mi][nf][j] * acc[mi][nf][j];
          ss += __shfl_xor(ss, 1, 64);
          ss += __shfl_xor(ss, 2, 64);
          ss += __shfl_xor(ss, 4, 64);
          ss += __shfl_xor(ss, 8, 64);
          float sc = rsqrtf(ss * (1.0f / 64.0f) + EPSF);
          size_t ob = ((size_t)(nn * NH_ + hh) * T_S + t) * 64;
#pragma unroll
          for (int nf = 0; nf < 2; ++nf) {
            int dd = nf * 16 + lrow;
            float cs = cosT[t * 32 + dd], sn = sinT[t * 32 + dd];
            float z1 = acc[mi][nf][j] * sc, z2 = acc[mi][nf + 2][j] * sc;
            dst[ob + dd] = f2bf(z1 * cs + z2 * sn);
            dst[ob + dd + 32] = f2bf(z2 * cs - z1 * sn);
          }
        }
    }
  }
}

// ---------------- chunked sliding-window attention (windowed) ----------------
// block = (n,h,c): 4 waves x 32 q-rows; wave w needs only key tiles
// ni in [2w, 2w+9] (keys (32w, 32w+159]); PV over 3 quarters qlo..qlo+2.
__global__ __launch_bounds__(256) void k_attn(const unsigned short* __restrict__ qh,
                                              const unsigned short* __restrict__ kh,
                                              const unsigned short* __restrict__ vh,
                                              unsigned short* __restrict__ ao) {
  extern __shared__ __align__(16) char lds[];
  unsigned short* Vt = (unsigned short*)lds;                    // [64][264]
  unsigned short* Pb = (unsigned short*)(lds + 64 * 264 * 2);   // 4 x [32][72]
  const int b = blockIdx.x;
  const int c = b & 31, nh = b >> 5;
  const int tid = threadIdx.x, lane = tid & 63, w = tid >> 6;
  const int lrow = lane & 15, g = lane >> 4, lk8 = g * 8;
  const size_t hb = (size_t)nh * T_S * 64;
  const unsigned short* qg = qh + hb + (size_t)c * 128 * 64;
  const unsigned short* kg = kh + hb + ((ptrdiff_t)c * 128 - 128) * 64;
  const unsigned short* vg = vh + hb + ((ptrdiff_t)c * 128 - 128) * 64;

  // stage V transposed via register 8x8 transpose, b128 writes
  {
    const int m_idx = (tid & 7) | ((tid >> 6) << 3);
    const int m0v = m_idx * 8;
    const int d0 = ((tid >> 3) & 7) * 8;
    short8 vv[8];
#pragma unroll
    for (int i = 0; i < 8; ++i) {
      short8 z = {0, 0, 0, 0, 0, 0, 0, 0};
      if (!(c == 0 && m0v < 128)) z = *(const short8*)(vg + (size_t)(m0v + i) * 64 + d0);
      vv[i] = z;
    }
#pragma unroll
    for (int jj = 0; jj < 8; ++jj) {
      short8 wv;
#pragma unroll
      for (int i = 0; i < 8; ++i) wv[i] = vv[i][jj];
      *(short8*)(Vt + (size_t)(d0 + jj) * 264 + m0v) = wv;
    }
  }

  // Q fragments
  bf16x8 qf[2][2];
#pragma unroll
  for (int mi = 0; mi < 2; ++mi)
#pragma unroll
    for (int ks = 0; ks < 2; ++ks)
      qf[mi][ks] =
          *(const bf16x8*)(qg + (size_t)(w * 32 + mi * 16 + lrow) * 64 + ks * 32 + lk8);

  // S = Q K^T over the wave's 10-tile window
  const int nlo = 2 * w;
  f32x4 s[2][10] = {};
#pragma unroll
  for (int u = 0; u < 10; ++u) {
    const int ni = nlo + u;
    if (c == 0 && ni < 8) continue;
    bf16x8 kf0 = *(const bf16x8*)(kg + (size_t)(ni * 16 + lrow) * 64 + lk8);
    bf16x8 kf1 = *(const bf16x8*)(kg + (size_t)(ni * 16 + lrow) * 64 + 32 + lk8);
#pragma unroll
    for (int mi = 0; mi < 2; ++mi) {
      s[mi][u] = mfma16(qf[mi][0], kf0, s[mi][u]);
      s[mi][u] = mfma16(qf[mi][1], kf1, s[mi][u]);
    }
  }

  // mask + scale + row softmax (deferred normalization)
  float invs[2][4];
#pragma unroll
  for (int mi = 0; mi < 2; ++mi) {
#pragma unroll
    for (int j = 0; j < 4; ++j) {
      int jq = w * 32 + mi * 16 + g * 4 + j;
      float mx = -1e30f;
#pragma unroll
      for (int u = 0; u < 10; ++u) {
        int m = (nlo + u) * 16 + lrow;
        bool ok = (m > jq) && (m <= 128 + jq) && (c > 0 || m >= 128);
        float val = ok ? s[mi][u][j] * 0.125f : -1e30f;
        s[mi][u][j] = val;
        mx = fmaxf(mx, val);
      }
#pragma unroll
      for (int d2 = 1; d2 < 16; d2 <<= 1) mx = fmaxf(mx, __shfl_xor(mx, d2, 64));
      float sum = 0.0f;
#pragma unroll
      for (int u = 0; u < 10; ++u) {
        float p = __expf(s[mi][u][j] - mx);
        s[mi][u][j] = p;
        sum += p;
      }
#pragma unroll
      for (int d2 = 1; d2 < 16; d2 <<= 1) sum += __shfl_xor(sum, d2, 64);
      invs[mi][j] = 1.0f / sum;
    }
  }

  __syncthreads();  // Vt staged before PV reads

  // PV over 3 quarters; P staged per-wave in LDS (stride 72), unnormalized
  f32x4 oacc[2][4] = {};
  unsigned short* Pw = Pb + w * (32 * 72);
  const int qlo = w >> 1;
#pragma unroll
  for (int qq = 0; qq < 3; ++qq) {
#pragma unroll
    for (int mi = 0; mi < 2; ++mi)
#pragma unroll
      for (int ni4 = 0; ni4 < 4; ++ni4)
#pragma unroll
        for (int j = 0; j < 4; ++j) {
          int r = mi * 16 + g * 4 + j;
          float val;
          if ((w & 1) == 0) {
            constexpr int base = 0;
            int u = qq * 4 + ni4 - base;
            val = (u >= 0 && u < 10) ? s[mi][(u >= 0 && u < 10) ? u : 0][j] : 0.0f;
          } else {
            int u = qq * 4 + ni4 - 2;
            val = (u >= 0 && u < 10) ? s[mi][(u >= 0 && u < 10) ? u : 0][j] : 0.0f;
          }
          Pw[r * 72 + ni4 * 16 + lrow] = f2bf(val);
        }
    const int qi = qlo + qq;
#pragma unroll
    for (int ks = 0; ks < 2; ++ks) {
      bf16x8 pf[2], vf[4];
#pragma unroll
      for (int mi = 0; mi < 2; ++mi)
        pf[mi] = *(const bf16x8*)&Pw[(mi * 16 + lrow) * 72 + ks * 32 + lk8];
#pragma unroll
      for (int nj = 0; nj < 4; ++nj)
        vf[nj] = *(const bf16x8*)&Vt[(nj * 16 + lrow) * 264 + qi * 64 + ks * 32 + lk8];
#pragma unroll
      for (int mi = 0; mi < 2; ++mi)
#pragma unroll
        for (int nj = 0; nj < 4; ++nj)
          oacc[mi][nj] = mfma16(pf[mi], vf[nj], oacc[mi][nj]);
    }
  }

  const int t0 = c * 128 + w * 32;
  const int n_ = nh >> 4, h_ = nh & 15;
#pragma unroll
  for (int mi = 0; mi < 2; ++mi)
#pragma unroll
    for (int nj = 0; nj < 4; ++nj)
#pragma unroll
      for (int j = 0; j < 4; ++j) {
        int t = t0 + mi * 16 + g * 4 + j;
        int dcol = nj * 16 + lrow;
        ao[((size_t)n_ * T_S + t) * D_M + h_ * 64 + dcol] =
            f2bf(oacc[mi][nj][j] * invs[mi][j]);
      }
}

extern "C" void kernel_launch(void* const* d_in, const int* in_sizes, int n_in,
                              void* d_out, int out_size, void* d_ws, size_t ws_size,
                              hipStream_t stream) {
  const float* x = (const float*)d_in[0];      // [2,4096,1024]
  const float* qkvw = (const float*)d_in[1];   // [3,1024,1024]
  const float* ow = (const float*)d_in[2];     // [1024,1024]
  const float* osc = (const float*)d_in[3];    // [1024]
  float* out = (float*)d_out;

  char* ws = (char*)d_ws;
  unsigned short* xn = (unsigned short*)(ws + 0);
  unsigned short* qkvwb = (unsigned short*)(ws + 16777216);
  unsigned short* owb = (unsigned short*)(ws + 23068672);
  unsigned short* qhb = (unsigned short*)(ws + 25165824);
  unsigned short* khb = (unsigned short*)(ws + 41943040);
  unsigned short* vhb = (unsigned short*)(ws + 58720256);
  unsigned short* aob = (unsigned short*)(ws + 75497472);
  float* cosT = (float*)(ws + 92274688);
  float* sinT = (float*)(ws + 92798976);

  k_rope_tab<<<512, 256, 0, stream>>>(cosT, sinT);
  k_f32_to_bf16<<<3072, 256, 0, stream>>>(qkvw, qkvwb);
  k_f32_to_bf16<<<1024, 256, 0, stream>>>(ow, owb);
  k_rmsnorm_cast<<<8192, 256, 0, stream>>>(x, xn);
  k_gemm256<0><<<dim3(24, 32), 512, 73728, stream>>>(xn, qkvwb, qhb, khb, vhb, nullptr,
                                                     nullptr, nullptr, cosT, sinT,
                                                     8192, 3072, 1024);
  k_attn<<<1024, 256, 52224, stream>>>(qhb, khb, vhb, aob);
  k_gemm256<1><<<dim3(8, 32), 512, 73728, stream>>>(aob, owb, nullptr, nullptr, nullptr,
                                                    out, x, osc, nullptr, nullptr,
                                                    8192, 1024, 1024);
}